// Round 9
// baseline (1332.243 us; speedup 1.0000x reference)
//
#include <hip/hip_runtime.h>
#include <hip/hip_fp16.h>

// IntersiteModel fused kernel — fp32 compute, round 11: fit the 84-VGPR budget.
// Post-mortem r10: min-waves knob rules the allocator: VGPR = 256/N exactly
// (2->128, 3->84, 4->64). N=3 gave best perf (1070us, VALUBusy 51%, occ 26%)
// but live sets >84 re-spilled (WRITE 39->110MB). This round keeps N=3 and
// trims every phase's base live set to <= ~84:
//   * stage-1 pass A k-halved: two t1h[24] passes (24+y40=64 base), weights
//     read twice (L2-hot).
//   * stage-2a ua/ub loops unroll 2->1 (one 32-wide weight row in flight).
//   * W3 contractions k-halved: zs/zv[16] (ua32+zs16=48 base).
//   * stage-2b: W2_10 / W2_11_1 un-merged (one row in flight each), unroll 1
//     (u1i32+g32+e12+row32 ~= 108 peak was the r10 spill hotspot at 140).
// Unchanged: y in 40 regs; x/t0/t1 fp16 half2 LDS (44 slots, 22528B/block);
// launch_bounds(TPB,3); no barriers (per-thread LDS columns).

#define TPB 128

__device__ __forceinline__ float sigf(float x) {
    return 1.0f / (1.0f + __expf(-x));
}

__global__ __launch_bounds__(TPB, 3)
void intersite_fused(const float* __restrict__ site1,
                     const float* __restrict__ site2,
                     const float* __restrict__ edge,
                     const float* __restrict__ W1_00,
                     const float* __restrict__ W1_11_0,
                     const float* __restrict__ W1_01,
                     const float* __restrict__ W1_10,
                     const float* __restrict__ W1_11_1,
                     const float* __restrict__ W2_00,
                     const float* __restrict__ W2_11_0,
                     const float* __restrict__ W2_01,
                     const float* __restrict__ W2_10,
                     const float* __restrict__ W2_11_1,
                     const float* __restrict__ W3_00,
                     const float* __restrict__ W3_11,
                     float* __restrict__ out, int B)
{
    __shared__ float lds[44 * TPB];
    const int t = threadIdx.x;
    const int b = blockIdx.x * TPB + t;
    if (b >= B) return;   // no barriers anywhere -> early return is safe

    const __half* ph = (const __half*)lds;
    __half2* ph2 = (__half2*)lds;
    // half H lives at half-index ((H>>1)*TPB + t)*2 + (H&1)
#define RDH(H) __half2float(ph[(((((H) >> 1) * TPB) + t) << 1) | ((H) & 1)])
#define WRH2(D, a, bb) ph2[(D) * TPB + t] = __floats2half2_rn((a), (bb))

    const float inv_s3   = 0.57735026918962576f;  // 1/sqrt(3)
    const float inv_s2   = 0.70710678118654752f;  // 1/sqrt(2)
    const float inv_s320 = 0.05590169943749474f;  // 1/sqrt(320)
    const float inv_s192 = 0.07216878364870323f;  // 1/sqrt(192)
    const float inv_s256 = 0.0625f;               // 1/sqrt(256)
    const float inv_s2048= 0.02209708691207961f;  // 1/sqrt(2048)

    // ---------------- stage x -> LDS fp16 (D0..19), y -> regs ----------------
    {
        const float4* p1 = (const float4*)(site1 + (size_t)b * 40);
        #pragma unroll
        for (int q = 0; q < 10; ++q) {
            float4 r = p1[q];
            WRH2(q*2+0, r.x, r.y);
            WRH2(q*2+1, r.z, r.w);
        }
    }
    float y0r[16], y1r[24];
    {
        const float4* p2 = (const float4*)(site2 + (size_t)b * 40);
        #pragma unroll
        for (int q = 0; q < 4; ++q) {
            float4 r = p2[q];
            y0r[q*4+0]=r.x; y0r[q*4+1]=r.y; y0r[q*4+2]=r.z; y0r[q*4+3]=r.w;
        }
        #pragma unroll
        for (int q = 0; q < 6; ++q) {
            float4 r = p2[4+q];
            y1r[q*4+0]=r.x; y1r[q*4+1]=r.y; y1r[q*4+2]=r.z; y1r[q*4+3]=r.w;
        }
    }

    // ---------------- stage 1, pass A: t1 in two k-halves ----------------
    // x half-index map: x0[u] -> H=u ; x1[u,i] -> H=16+u*3+i
    // output t1[K,i], K = kh*8 + kk; LDS H = 40 + K*3 + i
    #pragma unroll
    for (int kh = 0; kh < 2; ++kh) {
        float t1h[24];
        #pragma unroll
        for (int j = 0; j < 24; ++j) t1h[j] = 0.0f;

        // W1_01 (16,8,16): t1[K,i] += x0[u] y1[v,i] W[u,v,K]
        #pragma unroll 1
        for (int u = 0; u < 16; ++u) {
            float xu = RDH(u);
            const float* w01 = W1_01 + u * 128 + kh * 8;
            #pragma unroll
            for (int v = 0; v < 8; ++v) {
                float f0 = xu * y1r[v*3+0];
                float f1 = xu * y1r[v*3+1];
                float f2 = xu * y1r[v*3+2];
                #pragma unroll
                for (int kk = 0; kk < 8; ++kk) {
                    float w = w01[v*16+kk];
                    t1h[kk*3+0] = fmaf(f0, w, t1h[kk*3+0]);
                    t1h[kk*3+1] = fmaf(f1, w, t1h[kk*3+1]);
                    t1h[kk*3+2] = fmaf(f2, w, t1h[kk*3+2]);
                }
            }
        }
        // merged W1_10 (8,16,16) + W1_11_1 (8,8,16): share x1[u] reads
        #pragma unroll 1
        for (int u = 0; u < 8; ++u) {
            float ax = RDH(16+u*3+0), ay = RDH(16+u*3+1), az = RDH(16+u*3+2);
            const float* w10 = W1_10 + u * 256 + kh * 8;
            #pragma unroll
            for (int v = 0; v < 16; ++v) {
                float yv = y0r[v];
                float f0 = ax*yv, f1 = ay*yv, f2 = az*yv;
                #pragma unroll
                for (int kk = 0; kk < 8; ++kk) {
                    float w = w10[v*16+kk];
                    t1h[kk*3+0] = fmaf(f0, w, t1h[kk*3+0]);
                    t1h[kk*3+1] = fmaf(f1, w, t1h[kk*3+1]);
                    t1h[kk*3+2] = fmaf(f2, w, t1h[kk*3+2]);
                }
            }
            const float* w111 = W1_11_1 + u * 128 + kh * 8;
            #pragma unroll
            for (int v = 0; v < 8; ++v) {
                float bx = y1r[v*3], by = y1r[v*3+1], bz = y1r[v*3+2];
                float cx = (ay*bz - az*by) * inv_s2;
                float cy = (az*bx - ax*bz) * inv_s2;
                float cz = (ax*by - ay*bx) * inv_s2;
                #pragma unroll
                for (int kk = 0; kk < 8; ++kk) {
                    float w = w111[v*16+kk];
                    t1h[kk*3+0] = fmaf(cx, w, t1h[kk*3+0]);
                    t1h[kk*3+1] = fmaf(cy, w, t1h[kk*3+1]);
                    t1h[kk*3+2] = fmaf(cz, w, t1h[kk*3+2]);
                }
            }
        }
        // t1 half -> LDS fp16 (H = 40 + kh*24 + j, slots D20+kh*12..)
        #pragma unroll
        for (int m = 0; m < 12; ++m)
            WRH2(20 + kh*12 + m, t1h[2*m] * inv_s320, t1h[2*m+1] * inv_s320);
    }

    // ---------------- stage 1, pass B: t0[32] ----------------
    float t0[32];
    #pragma unroll
    for (int k = 0; k < 32; ++k) t0[k] = 0.0f;

    // W1_00 (16,16,32)
    #pragma unroll 1
    for (int u = 0; u < 16; ++u) {
        float xu = RDH(u);
        const float* w00 = W1_00 + u * 512;
        #pragma unroll
        for (int v = 0; v < 16; ++v) {
            float f = xu * y0r[v];
            #pragma unroll
            for (int k = 0; k < 32; ++k) t0[k] = fmaf(f, w00[v*32+k], t0[k]);
        }
    }
    // W1_11_0 (8,8,32)
    #pragma unroll 1
    for (int u = 0; u < 8; ++u) {
        float ax = RDH(16+u*3+0), ay = RDH(16+u*3+1), az = RDH(16+u*3+2);
        const float* w110 = W1_11_0 + u * 256;
        #pragma unroll
        for (int v = 0; v < 8; ++v) {
            float d = ax * y1r[v*3];
            d = fmaf(ay, y1r[v*3+1], d);
            d = fmaf(az, y1r[v*3+2], d);
            d *= inv_s3;
            #pragma unroll
            for (int k = 0; k < 32; ++k) t0[k] = fmaf(d, w110[v*32+k], t0[k]);
        }
    }
    // x dead now: t0 -> LDS fp16 at D0..15 (H = k)
    #pragma unroll
    for (int m = 0; m < 16; ++m)
        WRH2(m, t0[2*m] * inv_s320, t0[2*m+1] * inv_s320);

    // ---------------- edge -> regs ----------------
    float e0r[4], e1r[12];
    {
        const float4* pe = (const float4*)(edge + (size_t)b * 16);
        float4 r0 = pe[0], r1 = pe[1], r2 = pe[2], r3 = pe[3];
        e0r[0]=r0.x; e0r[1]=r0.y; e0r[2]=r0.z; e0r[3]=r0.w;
        e1r[0]=r1.x; e1r[1]=r1.y; e1r[2]=r1.z; e1r[3]=r1.w;
        e1r[4]=r2.x; e1r[5]=r2.y; e1r[6]=r2.z; e1r[7]=r2.w;
        e1r[8]=r3.x; e1r[9]=r3.y; e1r[10]=r3.z; e1r[11]=r3.w;
    }
    // t half-index map: t0[u] -> H=u ; t1[u,i] -> H=40+u*3+i

    float acc0 = 0.0f;
    // ---------------- stage 2a: u0 low half -> s -> acc0 ----------------
    {
        float ua[32];
        #pragma unroll
        for (int k = 0; k < 32; ++k) ua[k] = 0.0f;
        #pragma unroll 1
        for (int u = 0; u < 32; ++u) {
            float tu = RDH(u);
            const float* wu = W2_00 + u*256;
            #pragma unroll
            for (int v = 0; v < 4; ++v) {
                float f = tu * e0r[v];
                #pragma unroll
                for (int k = 0; k < 32; ++k) ua[k] = fmaf(f, wu[v*64+k], ua[k]);
            }
        }
        #pragma unroll 1
        for (int u = 0; u < 16; ++u) {
            float a0 = RDH(40+u*3+0), a1 = RDH(40+u*3+1), a2 = RDH(40+u*3+2);
            const float* wu = W2_11_0 + u*256;
            #pragma unroll
            for (int v = 0; v < 4; ++v) {
                float d = a0 * e1r[v*3];
                d = fmaf(a1, e1r[v*3+1], d);
                d = fmaf(a2, e1r[v*3+2], d);
                d *= inv_s3;
                #pragma unroll
                for (int k = 0; k < 32; ++k) ua[k] = fmaf(d, wu[v*64+k], ua[k]);
            }
        }
        #pragma unroll
        for (int k = 0; k < 32; ++k) {
            float x = ua[k] * inv_s192;
            ua[k] = x * sigf(x);
        }
        // acc0 = s^T W3_00 s, k-halved (zs[16] base live 48)
        #pragma unroll
        for (int h = 0; h < 2; ++h) {
            float zs[16];
            #pragma unroll
            for (int j = 0; j < 16; ++j) zs[j] = 0.0f;
            #pragma unroll
            for (int u = 0; u < 32; ++u) {
                const float* w = W3_00 + u*32 + h*16;
                #pragma unroll
                for (int j = 0; j < 16; ++j) zs[j] = fmaf(ua[u], w[j], zs[j]);
            }
            #pragma unroll
            for (int j = 0; j < 16; ++j) acc0 = fmaf(zs[j], ua[h*16+j], acc0);
        }
    }

    // ---------------- stage 2a': u0 high half -> g[32] ----------------
    float g[32];
    {
        float ub[32];
        #pragma unroll
        for (int k = 0; k < 32; ++k) ub[k] = 0.0f;
        #pragma unroll 1
        for (int u = 0; u < 32; ++u) {
            float tu = RDH(u);
            const float* wu = W2_00 + u*256 + 32;
            #pragma unroll
            for (int v = 0; v < 4; ++v) {
                float f = tu * e0r[v];
                #pragma unroll
                for (int k = 0; k < 32; ++k) ub[k] = fmaf(f, wu[v*64+k], ub[k]);
            }
        }
        #pragma unroll 1
        for (int u = 0; u < 16; ++u) {
            float a0 = RDH(40+u*3+0), a1 = RDH(40+u*3+1), a2 = RDH(40+u*3+2);
            const float* wu = W2_11_0 + u*256 + 32;
            #pragma unroll
            for (int v = 0; v < 4; ++v) {
                float d = a0 * e1r[v*3];
                d = fmaf(a1, e1r[v*3+1], d);
                d = fmaf(a2, e1r[v*3+2], d);
                d *= inv_s3;
                #pragma unroll
                for (int k = 0; k < 32; ++k) ub[k] = fmaf(d, wu[v*64+k], ub[k]);
            }
        }
        #pragma unroll
        for (int k = 0; k < 32; ++k) g[k] = sigf(ub[k] * inv_s192);
    }

    // ---------------- stage 2b+3: per-component u1_i -> gate -> acc1 -------
    float acc1 = 0.0f;
    const float* ep = edge + (size_t)b * 16 + 4;
    #pragma unroll 1
    for (int i = 0; i < 3; ++i) {
        int jj = (i == 2) ? 0 : i + 1;
        int kk = (jj == 2) ? 0 : jj + 1;
        float u1i[32];
        #pragma unroll
        for (int k = 0; k < 32; ++k) u1i[k] = 0.0f;

        // W2_01 (32,4,32): u1_i[k] += t0[u] e1[v,i] W[u,v,k]
        {
            float e1i[4];
            #pragma unroll
            for (int v = 0; v < 4; ++v) e1i[v] = ep[v*3 + i];
            #pragma unroll 1
            for (int u = 0; u < 32; ++u) {
                float tu = RDH(u);
                const float* wu = W2_01 + u*128;
                #pragma unroll
                for (int v = 0; v < 4; ++v) {
                    float f = tu * e1i[v];
                    #pragma unroll
                    for (int k = 0; k < 32; ++k) u1i[k] = fmaf(f, wu[v*32+k], u1i[k]);
                }
            }
        }
        // W2_10 (16,4,32): u1_i[k] += t1[u,i] e0[v] W[u,v,k]
        #pragma unroll 1
        for (int u = 0; u < 16; ++u) {
            float ai = RDH(40 + u*3 + i);
            const float* wa = W2_10 + u*128;
            #pragma unroll
            for (int v = 0; v < 4; ++v) {
                float f = ai * e0r[v];
                #pragma unroll
                for (int k = 0; k < 32; ++k) u1i[k] = fmaf(f, wa[v*32+k], u1i[k]);
            }
        }
        // W2_11_1 (16,4,32): u1_i[k] += (t1[u] x e1[v])_i /sqrt2 W[u,v,k]
        {
            float e1j[4], e1k4[4];
            #pragma unroll
            for (int v = 0; v < 4; ++v) { e1j[v] = ep[v*3 + jj]; e1k4[v] = ep[v*3 + kk]; }
            #pragma unroll 1
            for (int u = 0; u < 16; ++u) {
                float aj = RDH(40 + u*3 + jj);
                float ak = RDH(40 + u*3 + kk);
                const float* wb = W2_11_1 + u*128;
                #pragma unroll
                for (int v = 0; v < 4; ++v) {
                    float c = (aj * e1k4[v] - ak * e1j[v]) * inv_s2;
                    #pragma unroll
                    for (int k = 0; k < 32; ++k) u1i[k] = fmaf(c, wb[v*32+k], u1i[k]);
                }
            }
        }
        // gate: v_i = (u1_i/sqrt256) * g ; acc1 += v_i^T W3_11 v_i (k-halved)
        #pragma unroll
        for (int k = 0; k < 32; ++k) u1i[k] = u1i[k] * inv_s256 * g[k];
        #pragma unroll
        for (int h = 0; h < 2; ++h) {
            float zv[16];
            #pragma unroll
            for (int j = 0; j < 16; ++j) zv[j] = 0.0f;
            #pragma unroll
            for (int u = 0; u < 32; ++u) {
                const float* w = W3_11 + u*32 + h*16;
                #pragma unroll
                for (int j = 0; j < 16; ++j) zv[j] = fmaf(u1i[u], w[j], zv[j]);
            }
            #pragma unroll
            for (int j = 0; j < 16; ++j) acc1 = fmaf(zv[j], u1i[h*16+j], acc1);
        }
    }

    out[b] = (acc0 + acc1 * inv_s3) * inv_s2048;
#undef RDH
#undef WRH2
}

extern "C" void kernel_launch(void* const* d_in, const int* in_sizes, int n_in,
                              void* d_out, int out_size, void* d_ws, size_t ws_size,
                              hipStream_t stream)
{
    const float* site1   = (const float*)d_in[0];
    const float* site2   = (const float*)d_in[1];
    const float* edge    = (const float*)d_in[2];
    const float* W1_00   = (const float*)d_in[3];
    const float* W1_11_0 = (const float*)d_in[4];
    const float* W1_01   = (const float*)d_in[5];
    const float* W1_10   = (const float*)d_in[6];
    const float* W1_11_1 = (const float*)d_in[7];
    const float* W2_00   = (const float*)d_in[8];
    const float* W2_11_0 = (const float*)d_in[9];
    const float* W2_01   = (const float*)d_in[10];
    const float* W2_10   = (const float*)d_in[11];
    const float* W2_11_1 = (const float*)d_in[12];
    const float* W3_00   = (const float*)d_in[13];
    const float* W3_11   = (const float*)d_in[14];
    float* out = (float*)d_out;

    const int B = in_sizes[0] / 40;
    dim3 grid((B + TPB - 1) / TPB), block(TPB);
    hipLaunchKernelGGL(intersite_fused, grid, block, 0, stream,
                       site1, site2, edge,
                       W1_00, W1_11_0, W1_01, W1_10, W1_11_1,
                       W2_00, W2_11_0, W2_01, W2_10, W2_11_1,
                       W3_00, W3_11, out, B);
}